// Round 6
// baseline (269.068 us; speedup 1.0000x reference)
//
#include <hip/hip_runtime.h>
#include <math.h>

#define CCH 512      // channels
#define FH 76        // feature H
#define FW 128       // feature W
#define NP 256       // proposals
#define HID 200      // hidden width
#define NKC 16       // K-chunks for layer1 split-K (128 k each)
#define FM4 (FH * FW * (CCH / 4))      // 1,245,184 float4 in feature map
#define NBLK 256
#define NTHR 512
#define NTH_ALL (NBLK * NTHR)          // 131,072 threads grid-wide

// ---- ws layout ----
// f    : [256][2048] fp32  (2.10 MB)
// part : [16][256][200]    (4.10 MB)
// bar  : 256 ints (4 barrier slots x 64-int stride)
// scratch : DCE guard target

// ---------------- init: zero grid-barrier slots (ws is 0xAA-poisoned) ----
__global__ __launch_bounds__(256) void init_kernel(int* __restrict__ bar)
{
    bar[threadIdx.x] = 0;
}

// Software grid barrier: all 256 blocks are co-resident by capacity
// (256 blocks <= 256 CUs, ~3KB LDS, launch_bounds(512,2) caps VGPR<=256,
// so every CU can hold >=1 block regardless of placement). Device-scope
// atomics + __threadfence (L2 wb/inv on gfx950) give cross-XCD visibility.
__device__ __forceinline__ void grid_barrier(int* bar, int idx)
{
    __syncthreads();                      // all waves' vm writes drained
    if (threadIdx.x == 0) {
        int* cnt  = bar + idx * 64;
        int* flag = bar + idx * 64 + 32;  // separate 128B line
        __threadfence();                  // release: flush block's writes
        const int old = __hip_atomic_fetch_add(cnt, 1, __ATOMIC_ACQ_REL,
                                               __HIP_MEMORY_SCOPE_AGENT);
        if (old == NBLK - 1) {
            __hip_atomic_store(flag, 1, __ATOMIC_RELEASE,
                               __HIP_MEMORY_SCOPE_AGENT);
        } else {
            while (!__hip_atomic_load(flag, __ATOMIC_ACQUIRE,
                                      __HIP_MEMORY_SCOPE_AGENT))
                __builtin_amdgcn_s_sleep(2);
        }
        __threadfence();                  // acquire: invalidate stale lines
    }
    __syncthreads();
}

// ---------------- fused: warm -> pool -> l1 -> head ----------------
__global__ __launch_bounds__(NTHR, 2) void fused_kernel(
    const float4* __restrict__ fm4, const int* __restrict__ coords,
    const float* __restrict__ W1, const float* __restrict__ b1,
    const float* __restrict__ W2, const float* __restrict__ b2,
    const float* __restrict__ W3, const float* __restrict__ b3,
    const float* __restrict__ W4, const float* __restrict__ b4,
    float* __restrict__ f, float* __restrict__ part,
    int* __restrict__ bar, float* __restrict__ scratch,
    float* __restrict__ out)
{
    const int blk = blockIdx.x;
    const int t   = threadIdx.x;
    const int gtid = blk * NTHR + t;

    // ===== Phase A: cooperative cache warm (fm + all weights) =====
    // ws poison (256 MiB fill) cycles all of L3 every iteration, so every
    // input is HBM-cold. Stream them coalesced at HBM BW; later scattered /
    // strided reads then hit L2/L3 (~200cyc) instead of cold HBM (~900cyc).
    float wacc = -1e30f;
    #pragma unroll
    for (int i = 0; i < 10; ++i) {                  // fm: 10 x 131072 >= FM4
        const int idx = gtid + i * NTH_ALL;
        if (idx < FM4) {
            const float4 v = fm4[idx];
            wacc = fmaxf(wacc, fmaxf(fmaxf(v.x, v.y), fmaxf(v.z, v.w)));
        }
    }
    {   // W1: 2048*200 fp32 = 102400 float4 (< 131072)
        const float4* w14 = (const float4*)W1;
        if (gtid < 102400) {
            const float4 v = w14[gtid];
            wacc = fmaxf(wacc, fmaxf(fmaxf(v.x, v.y), fmaxf(v.z, v.w)));
        }
        // W2 (10000 f4) + W3 (800 f4) + W4 (250 f4)
        const float4* w24 = (const float4*)W2;
        if (gtid < 10000) {
            const float4 v = w24[gtid];
            wacc = fmaxf(wacc, fmaxf(fmaxf(v.x, v.y), fmaxf(v.z, v.w)));
        }
        const float4* w34 = (const float4*)W3;
        if (gtid < 800) {
            const float4 v = w34[gtid];
            wacc = fmaxf(wacc, fmaxf(fmaxf(v.x, v.y), fmaxf(v.z, v.w)));
        }
        const float4* w44 = (const float4*)W4;
        if (gtid < 250) {
            const float4 v = w44[gtid];
            wacc = fmaxf(wacc, fmaxf(fmaxf(v.x, v.y), fmaxf(v.z, v.w)));
        }
    }
    // DCE guard: data-dependent, never true for N(0,1)-scale inputs.
    if (wacc > 1e29f) scratch[0] = wacc;

    grid_barrier(bar, 0);

    // ===== Phase B: ROI adaptive 2x2 max-pool (block = proposal) =====
    {
        const int n   = blk;
        const int bin = t >> 7;          // wave-uniform: 2 waves per bin
        const int by = bin >> 1, bx = bin & 1;
        const int cg = t & 127;          // float4 group of channels
        const int c0 = coords[n*4+0], c1 = coords[n*4+1];
        const int c2 = coords[n*4+2], c3 = coords[n*4+3];
        const int sy = min(c0 >> 3, FH - 2);
        const int sx = min(c1 >> 3, FW - 2);
        const int h = max(((c2 + 7) >> 3) - sy, 2);
        const int w = max(((c3 + 7) >> 3) - sx, 2);
        const int rs = by ? (h >> 1) : 0;
        const int re = by ? h : ((h + 1) >> 1);
        const int cs = bx ? (w >> 1) : 0;
        const int ce = bx ? w : ((w + 1) >> 1);
        const int nc = ce - cs;
        float4 m = make_float4(-1e30f, -1e30f, -1e30f, -1e30f);
        for (int r = rs; r < re; ++r) {
            const float4* row = fm4 + ((size_t)(sy + r) * FW + sx + cs) * (CCH/4) + cg;
            #pragma unroll 4
            for (int cc = 0; cc < nc; ++cc) {
                const float4 v = row[(size_t)cc * (CCH/4)];
                m.x = fmaxf(m.x, v.x); m.y = fmaxf(m.y, v.y);
                m.z = fmaxf(m.z, v.z); m.w = fmaxf(m.w, v.w);
            }
        }
        ((float4*)f)[(size_t)n * (4*CCH/4) + bin * (CCH/4) + cg] = m;
    }

    grid_barrier(bar, 1);

    // ===== Phase C: layer1 split-K GEMM partials =====
    // block = (row-tile of 8, kc-pair); halves of the block take kc*2, kc*2+1.
    {
        const int r0   = (blk >> 3) * 8;          // 32 row-tiles
        const int half = t >> 8;                  // 0..1, wave-uniform
        const int kc   = (blk & 7) * 2 + half;    // 0..15
        const int k0   = kc * 128;
        const int j    = t & 255;
        if (j < HID) {
            float acc[8];
            #pragma unroll
            for (int r = 0; r < 8; ++r) acc[r] = 0.0f;
            const float* fp = f  + (size_t)r0 * 2048 + k0;  // wave-uniform -> s_load
            const float* wp = W1 + (size_t)k0 * HID + j;    // coalesced across j
            #pragma unroll 8
            for (int k = 0; k < 128; ++k) {
                const float wv = wp[(size_t)k * HID];
                #pragma unroll
                for (int r = 0; r < 8; ++r)
                    acc[r] += fp[(size_t)r * 2048 + k] * wv;
            }
            float* pp = part + ((size_t)kc * NP + r0) * HID + j;
            #pragma unroll
            for (int r = 0; r < 8; ++r)
                pp[(size_t)r * HID] = acc[r];
        }
    }

    grid_barrier(bar, 2);

    // ===== Phase D: reduce + layer2 + heads + box decode (block = proposal) =====
    {
        __shared__ float h1s[HID];
        __shared__ float h2s[HID];
        __shared__ float p2[2][HID];
        __shared__ float hdp[2][21];
        __shared__ float hd[21];
        const int n = blk;
        const int kc = t >> 8;       // 0..1, wave-uniform
        const int j  = t & 255;
        if (t < HID) {
            float a = b1[t];
            #pragma unroll
            for (int c = 0; c < NKC; ++c)
                a += part[((size_t)c * NP + n) * HID + t];
            h1s[t] = fmaxf(a, 0.0f);
        }
        __syncthreads();
        if (j < HID) {
            const int k0 = kc * 100;
            float acc = 0.0f;
            #pragma unroll 10
            for (int k = 0; k < 100; ++k)
                acc += h1s[k0 + k] * W2[(k0 + k) * HID + j];
            p2[kc][j] = acc;
        }
        __syncthreads();
        if (t < HID) h2s[t] = fmaxf(p2[0][t] + p2[1][t] + b2[t], 0.0f);
        __syncthreads();
        if (j < 21) {
            const int k0 = kc * 100;
            float acc = 0.0f;
            if (j < 16) {
                #pragma unroll 5
                for (int k = 0; k < 100; ++k)
                    acc += h2s[k0 + k] * W3[(k0 + k) * 16 + j];
            } else {
                const int ci = j - 16;
                #pragma unroll 5
                for (int k = 0; k < 100; ++k)
                    acc += h2s[k0 + k] * W4[(k0 + k) * 5 + ci];
            }
            hdp[kc][j] = acc;
        }
        __syncthreads();
        if (t < 21)
            hd[t] = hdp[0][t] + hdp[1][t] + (t < 16 ? b3[t] : b4[t - 16]);
        __syncthreads();
        if (t == 0) {
            const float cv0 = hd[16], cv1 = hd[17], cv2 = hd[18],
                        cv3 = hd[19], cv4 = hd[20];
            // jnp.argmax: first occurrence of max -> strict '>'
            int cls = 0; float best = cv0;
            if (cv1 > best) { best = cv1; cls = 1; }
            if (cv2 > best) { best = cv2; cls = 2; }
            if (cv3 > best) { best = cv3; cls = 3; }
            if (cv4 > best) { best = cv4; cls = 4; }
            const float e0 = expf(cv0 - best), e1 = expf(cv1 - best),
                        e2 = expf(cv2 - best), e3 = expf(cv3 - best),
                        e4 = expf(cv4 - best);
            const float s = e0 + e1 + e2 + e3 + e4;
            const float score = fmaxf(fmaxf(e1, e2), fmaxf(e3, e4)) / s;
            const int ri = max(cls - 1, 0);
            const float rg0 = hd[ri*4+0], rg1 = hd[ri*4+1],
                        rg2 = hd[ri*4+2], rg3 = hd[ri*4+3];
            const float y0 = (float)coords[n*4+0], x0 = (float)coords[n*4+1];
            const float y1 = (float)coords[n*4+2], x1 = (float)coords[n*4+3];
            const float ph = y1 - y0, pw = x1 - x0;
            const float py = y0 + 0.5f * ph, px = x0 + 0.5f * pw;
            const float oy = ph * rg0 + py;
            const float ox = pw * rg1 + px;
            const float oh = ph * fminf(fmaxf(expf(rg2), 0.001f), 20.0f);
            const float ow = pw * fminf(fmaxf(expf(rg3), 0.001f), 20.0f);
            out[n*4+0] = oy; out[n*4+1] = ox; out[n*4+2] = oh; out[n*4+3] = ow;
            out[NP*4 + n] = score;                       // scores block
            out[NP*5 + n] = (cls != 0) ? 1.0f : 0.0f;    // mask block
        }
    }
}

extern "C" void kernel_launch(void* const* d_in, const int* in_sizes, int n_in,
                              void* d_out, int out_size, void* d_ws, size_t ws_size,
                              hipStream_t stream) {
    const float* fm     = (const float*)d_in[0];   // [1,76,128,512]
    const int*   coords = (const int*)  d_in[1];   // [256,4]
    const float* W1 = (const float*)d_in[2];       // [2048,200]
    const float* b1 = (const float*)d_in[3];
    const float* W2 = (const float*)d_in[4];       // [200,200]
    const float* b2 = (const float*)d_in[5];
    const float* W3 = (const float*)d_in[6];       // [200,16]
    const float* b3 = (const float*)d_in[7];
    const float* W4 = (const float*)d_in[8];       // [200,5]
    const float* b4 = (const float*)d_in[9];
    float* out = (float*)d_out;

    float* f       = (float*)d_ws;                 // [256,2048]
    float* part    = f + (size_t)NP * 2048;        // [16,256,200]
    int*   bar     = (int*)(part + (size_t)NKC * NP * HID);  // 256 ints
    float* scratch = (float*)(bar + 256);

    init_kernel<<<1, 256, 0, stream>>>(bar);
    fused_kernel<<<NBLK, NTHR, 0, stream>>>(
        (const float4*)fm, coords, W1, b1, W2, b2, W3, b3, W4, b4,
        f, part, bar, scratch, out);
}

// Round 7
// 133.213 us; speedup vs baseline: 2.0198x; 2.0198x over previous
//
#include <hip/hip_runtime.h>
#include <math.h>

#define CCH 512      // channels
#define FH 76        // feature H
#define FW 128       // feature W
#define NP 256       // proposals
#define HID 200      // hidden width
#define NKC 16       // K-chunks for layer1 split-K
#define L1_KC 128    // K per chunk
#define L1_ROWS 8    // proposals per l1 block
#define FM4 (FH * FW * (CCH / 4))      // 1,245,184 float4 in feature map
#define POOL_THREADS (NP * 4 * 512)    // 524,288 threads in pool grid

// ---------------- Kernel 1: warm + ROI adaptive 2x2 max-pool ----------------
// Phase A: cooperative coalesced stream of fm AND all weight matrices.
// The harness restores inputs then poisons 268MB of ws (= full L3) every
// iteration, so every input is HBM-cold at kernel start. Streaming pulls
// them into L2/L3 so Phase B's scattered reads and the l1/head kernels'
// weight loads hit cache (~200cyc) instead of cold HBM (~900cyc).
// NOTE (R5/R6): separate warm dispatch costs more than its ordering gain
// (+1.8us), and software grid barriers cost ~50us each at 256 blocks —
// fused, unordered warm is the measured optimum.
// Phase B: grid (256 proposals, 4 bins), block 512 = 4 row-slots x 128
// float4 channel-groups; LDS reduce over row-slots.
__global__ __launch_bounds__(512) void pool_kernel(
    const float4* __restrict__ fm4, const int* __restrict__ coords,
    const float4* __restrict__ W1, const float4* __restrict__ W2,
    const float4* __restrict__ W3, const float4* __restrict__ W4,
    float4* __restrict__ f4, float* __restrict__ scratch)
{
    __shared__ float4 smem[4][128];
    const int n   = blockIdx.x;
    const int bin = blockIdx.y;
    const int t   = threadIdx.x;

    // ---- Phase A: warm (fm: 3 loads/thread; weights: subsets) ----
    const int gtid = (blockIdx.y * NP + blockIdx.x) * 512 + t;
    float wacc = -1e30f;
    #pragma unroll
    for (int i = 0; i < 3; ++i) {
        const int idx = gtid + i * POOL_THREADS;
        if (idx < FM4) {
            const float4 v = fm4[idx];
            wacc = fmaxf(wacc, fmaxf(fmaxf(v.x, v.y), fmaxf(v.z, v.w)));
        }
    }
    if (gtid < 102400) {                       // W1: 2048*200/4 float4
        const float4 v = W1[gtid];
        wacc = fmaxf(wacc, fmaxf(fmaxf(v.x, v.y), fmaxf(v.z, v.w)));
    }
    if (gtid < 10000) {                        // W2: 200*200/4
        const float4 v = W2[gtid];
        wacc = fmaxf(wacc, fmaxf(fmaxf(v.x, v.y), fmaxf(v.z, v.w)));
    }
    if (gtid < 800) {                          // W3: 200*16/4
        const float4 v = W3[gtid];
        wacc = fmaxf(wacc, fmaxf(fmaxf(v.x, v.y), fmaxf(v.z, v.w)));
    }
    if (gtid < 250) {                          // W4: 200*5/4
        const float4 v = W4[gtid];
        wacc = fmaxf(wacc, fmaxf(fmaxf(v.x, v.y), fmaxf(v.z, v.w)));
    }
    // DCE guard: data-dependent, never true for N(0,1)-scale inputs.
    if (wacc > 1e29f) scratch[0] = wacc;

    // ---- Phase B: scattered ROI reads ----
    const int by = bin >> 1, bx = bin & 1;
    const int rslot = t >> 7;        // 0..3
    const int cg    = t & 127;       // float4 group: channels 4*cg..4*cg+3
    const int c0 = coords[n*4+0], c1 = coords[n*4+1];
    const int c2 = coords[n*4+2], c3 = coords[n*4+3];
    const int sy = min(c0 >> 3, FH - 2);
    const int sx = min(c1 >> 3, FW - 2);
    const int h = max(((c2 + 7) >> 3) - sy, 2);
    const int w = max(((c3 + 7) >> 3) - sx, 2);
    // adaptive bin i covers [i*size/2, ((i+1)*size+1)/2)
    const int rs = by ? (h >> 1) : 0;
    const int re = by ? h : ((h + 1) >> 1);
    const int cs = bx ? (w >> 1) : 0;
    const int ce = bx ? w : ((w + 1) >> 1);
    const int nc = ce - cs;          // 1..12 cols in this bin
    float4 m = make_float4(-1e30f, -1e30f, -1e30f, -1e30f);
    for (int r = rs + rslot; r < re; r += 4) {
        const float4* row = fm4 + ((size_t)(sy + r) * FW + sx + cs) * (CCH/4) + cg;
        #pragma unroll 4
        for (int cc = 0; cc < nc; ++cc) {
            const float4 v = row[(size_t)cc * (CCH/4)];
            m.x = fmaxf(m.x, v.x); m.y = fmaxf(m.y, v.y);
            m.z = fmaxf(m.z, v.z); m.w = fmaxf(m.w, v.w);
        }
    }
    smem[rslot][cg] = m;
    __syncthreads();
    if (t < 128) {
        float4 a = smem[0][t], b = smem[1][t];
        float4 c = smem[2][t], d = smem[3][t];
        float4 o;
        o.x = fmaxf(fmaxf(a.x, b.x), fmaxf(c.x, d.x));
        o.y = fmaxf(fmaxf(a.y, b.y), fmaxf(c.y, d.y));
        o.z = fmaxf(fmaxf(a.z, b.z), fmaxf(c.z, d.z));
        o.w = fmaxf(fmaxf(a.w, b.w), fmaxf(c.w, d.w));
        f4[(size_t)n * (4*CCH/4) + bin * (CCH/4) + t] = o;
    }
}

// ---------------- Kernel 2: layer1 split-K GEMM, partials (no atomics) ---
// part[kc][n][j] = sum_{k in chunk kc} f[n][k] * W1[k][j]
// grid (32 row-tiles, 16 k-chunks), block 256 (thread j = output column).
// W1 is L2-warm from pool's Phase A; unroll 16 -> 8 load batches in flight.
__global__ __launch_bounds__(256) void l1_kernel(
    const float* __restrict__ f, const float* __restrict__ W1,
    float* __restrict__ part)
{
    const int j = threadIdx.x;
    if (j >= HID) return;
    const int r0 = blockIdx.x * L1_ROWS;
    const int kc = blockIdx.y;
    const int k0 = kc * L1_KC;
    float acc[L1_ROWS];
    #pragma unroll
    for (int r = 0; r < L1_ROWS; ++r) acc[r] = 0.0f;
    const float* fp = f  + (size_t)r0 * 2048 + k0;   // wave-uniform -> s_load path
    const float* wp = W1 + (size_t)k0 * HID + j;     // coalesced across j
    #pragma unroll 16
    for (int k = 0; k < L1_KC; ++k) {
        const float wv = wp[(size_t)k * HID];
        #pragma unroll
        for (int r = 0; r < L1_ROWS; ++r)
            acc[r] += fp[(size_t)r * 2048 + k] * wv;
    }
    float* pp = part + ((size_t)kc * NP + r0) * HID + j;
    #pragma unroll
    for (int r = 0; r < L1_ROWS; ++r)
        pp[(size_t)r * HID] = acc[r];
}

// ---------------- Kernel 3: reduce + layer2 + heads + postprocess --------
// One block (512 threads) per proposal; layer2 and heads are split over
// 2 K-halves (kc = t>>8, wave-uniform) to halve the serial load chains.
__global__ __launch_bounds__(512) void head_kernel(
    const float* __restrict__ part,
    const float* __restrict__ b1, const float* __restrict__ W2,
    const float* __restrict__ b2, const float* __restrict__ W3,
    const float* __restrict__ b3, const float* __restrict__ W4,
    const float* __restrict__ b4, const int* __restrict__ coords,
    float* __restrict__ out)
{
    __shared__ float h1s[HID];
    __shared__ float h2s[HID];
    __shared__ float p2[2][HID];
    __shared__ float hdp[2][21];
    __shared__ float hd[21];     // 16 reg + 5 cls
    const int n = blockIdx.x;
    const int t = threadIdx.x;
    const int kc = t >> 8;       // 0..1, wave-uniform
    const int j  = t & 255;
    if (t < HID) {
        float a = b1[t];
        #pragma unroll
        for (int c = 0; c < NKC; ++c)
            a += part[((size_t)c * NP + n) * HID + t];
        h1s[t] = fmaxf(a, 0.0f);
    }
    __syncthreads();
    if (j < HID) {
        const int k0 = kc * 100;
        float acc = 0.0f;
        #pragma unroll 10
        for (int k = 0; k < 100; ++k)
            acc += h1s[k0 + k] * W2[(k0 + k) * HID + j];
        p2[kc][j] = acc;
    }
    __syncthreads();
    if (t < HID) h2s[t] = fmaxf(p2[0][t] + p2[1][t] + b2[t], 0.0f);
    __syncthreads();
    if (j < 21) {
        const int k0 = kc * 100;
        float acc = 0.0f;
        if (j < 16) {
            #pragma unroll 5
            for (int k = 0; k < 100; ++k)
                acc += h2s[k0 + k] * W3[(k0 + k) * 16 + j];
        } else {
            const int ci = j - 16;
            #pragma unroll 5
            for (int k = 0; k < 100; ++k)
                acc += h2s[k0 + k] * W4[(k0 + k) * 5 + ci];
        }
        hdp[kc][j] = acc;
    }
    __syncthreads();
    if (t < 21)
        hd[t] = hdp[0][t] + hdp[1][t] + (t < 16 ? b3[t] : b4[t - 16]);
    __syncthreads();
    if (t == 0) {
        const float cv0 = hd[16], cv1 = hd[17], cv2 = hd[18],
                    cv3 = hd[19], cv4 = hd[20];
        // jnp.argmax: first occurrence of max -> strict '>'
        int cls = 0; float best = cv0;
        if (cv1 > best) { best = cv1; cls = 1; }
        if (cv2 > best) { best = cv2; cls = 2; }
        if (cv3 > best) { best = cv3; cls = 3; }
        if (cv4 > best) { best = cv4; cls = 4; }
        const float e0 = expf(cv0 - best), e1 = expf(cv1 - best),
                    e2 = expf(cv2 - best), e3 = expf(cv3 - best),
                    e4 = expf(cv4 - best);
        const float s = e0 + e1 + e2 + e3 + e4;
        const float score = fmaxf(fmaxf(e1, e2), fmaxf(e3, e4)) / s;
        const int ri = max(cls - 1, 0);
        const float rg0 = hd[ri*4+0], rg1 = hd[ri*4+1],
                    rg2 = hd[ri*4+2], rg3 = hd[ri*4+3];
        const float y0 = (float)coords[n*4+0], x0 = (float)coords[n*4+1];
        const float y1 = (float)coords[n*4+2], x1 = (float)coords[n*4+3];
        const float ph = y1 - y0, pw = x1 - x0;
        const float py = y0 + 0.5f * ph, px = x0 + 0.5f * pw;
        const float oy = ph * rg0 + py;
        const float ox = pw * rg1 + px;
        const float oh = ph * fminf(fmaxf(expf(rg2), 0.001f), 20.0f);
        const float ow = pw * fminf(fmaxf(expf(rg3), 0.001f), 20.0f);
        out[n*4+0] = oy; out[n*4+1] = ox; out[n*4+2] = oh; out[n*4+3] = ow;
        out[NP*4 + n] = score;                       // scores block
        out[NP*5 + n] = (cls != 0) ? 1.0f : 0.0f;    // mask block (bool as fp32)
    }
}

extern "C" void kernel_launch(void* const* d_in, const int* in_sizes, int n_in,
                              void* d_out, int out_size, void* d_ws, size_t ws_size,
                              hipStream_t stream) {
    const float* fm     = (const float*)d_in[0];   // [1,76,128,512]
    const int*   coords = (const int*)  d_in[1];   // [256,4]
    const float* W1 = (const float*)d_in[2];       // [2048,200]
    const float* b1 = (const float*)d_in[3];
    const float* W2 = (const float*)d_in[4];       // [200,200]
    const float* b2 = (const float*)d_in[5];
    const float* W3 = (const float*)d_in[6];       // [200,16]
    const float* b3 = (const float*)d_in[7];
    const float* W4 = (const float*)d_in[8];       // [200,5]
    const float* b4 = (const float*)d_in[9];
    float* out = (float*)d_out;                    // 1024 boxes + 256 scores + 256 mask

    float* f       = (float*)d_ws;                 // [256, 2048]
    float* part    = f + (size_t)NP * 2048;        // [16, 256, 200]
    float* scratch = part + (size_t)NKC * NP * HID;

    pool_kernel<<<dim3(NP, 4), 512, 0, stream>>>(
        (const float4*)fm, coords, (const float4*)W1, (const float4*)W2,
        (const float4*)W3, (const float4*)W4, (float4*)f, scratch);
    l1_kernel  <<<dim3(NP / L1_ROWS, NKC), 256, 0, stream>>>(f, W1, part);
    head_kernel<<<NP, 512, 0, stream>>>(part, b1, W2, b2, W3, b3, W4, b4,
                                        coords, out);
}

// Round 8
// 120.577 us; speedup vs baseline: 2.2315x; 1.1048x over previous
//
#include <hip/hip_runtime.h>
#include <math.h>

#define CCH 512      // channels
#define FH 76        // feature H
#define FW 128       // feature W
#define NP 256       // proposals
#define HID 200      // hidden width
#define NKC 16       // K-chunks for layer1 split-K (128 k each)
#define FM4 (FH * FW * (CCH / 4))      // 1,245,184 float4 in feature map
#define PG_THREADS (512 * 512)         // threads in poolgemm grid

// ---------------- Kernel 1: fused warm + ROI-pool + layer1 split-K ------
// Key structure: the (row-tile, kc) split-K grid EXACTLY tiles the pooled
// feature matrix f[256][2048]: k-chunk kc covers bin kc>>2, channel block
// (kc&3)*128. So each block pools its own [8 proposals x 128 channels]
// f-subtile into LDS and immediately GEMMs it against its W1 chunk —
// no inter-block dependency, no f global round-trip, one fewer dispatch.
// Phase A warm (R4's best-measured recipe): fm is HBM-cold every iteration
// (the harness's 268MB ws poison cycles all of L3); stream it coalesced at
// HBM BW so the scattered pool reads hit L2/L3. W1 streamed too (GEMM use).
// R6 lesson: software grid barriers cost ~50us each at 256 blocks; R5
// lesson: a separate warm dispatch costs more than its ordering gain —
// fused, unordered warm wins.
__global__ __launch_bounds__(512) void poolgemm_kernel(
    const float4* __restrict__ fm4, const int* __restrict__ coords,
    const float* __restrict__ W1, float* __restrict__ part,
    float* __restrict__ scratch)
{
    __shared__ float4 sm[2][8][32];    // rslot x proposal x f4-group (8 KB)
    __shared__ float  fsub[8][128];    // pooled subtile (4 KB)
    __shared__ float  pc[2][8][HID];   // K-half partials (12.8 KB)

    const int t   = threadIdx.x;
    const int r0  = blockIdx.x * 8;          // 32 row-tiles
    const int kc  = blockIdx.y;              // 0..15
    const int bin = kc >> 2;
    const int cb  = (kc & 3) * 32;           // f4-group offset inside bin
    const int k0  = kc * 128;                // global k offset

    // ===== Phase A: cooperative cache warm (fm + W1) =====
    {
        const int gtid = (blockIdx.y * 32 + blockIdx.x) * 512 + t;
        float wacc = -1e30f;
        #pragma unroll
        for (int i = 0; i < 5; ++i) {        // 5 x 262144 >= FM4
            const int idx = gtid + i * PG_THREADS;
            if (idx < FM4) {
                const float4 v = fm4[idx];
                wacc = fmaxf(wacc, fmaxf(fmaxf(v.x, v.y), fmaxf(v.z, v.w)));
            }
        }
        if (gtid < 102400) {                 // W1: 2048*200/4 float4
            const float4 v = ((const float4*)W1)[gtid];
            wacc = fmaxf(wacc, fmaxf(fmaxf(v.x, v.y), fmaxf(v.z, v.w)));
        }
        // DCE guard: data-dependent, never true for N(0,1)-scale inputs.
        if (wacc > 1e29f) scratch[0] = wacc;
    }

    // ===== Phase B: pool this block's [8 proposals x 128 ch] subtile =====
    {
        const int rslot = t >> 8;            // 0..1 (wave-uniform)
        const int nl    = (t >> 5) & 7;      // proposal within tile
        const int cg    = t & 31;            // f4-group within chunk
        const int n  = r0 + nl;
        const int c0 = coords[n*4+0], c1 = coords[n*4+1];
        const int c2 = coords[n*4+2], c3 = coords[n*4+3];
        const int sy = min(c0 >> 3, FH - 2);
        const int sx = min(c1 >> 3, FW - 2);
        const int h = max(((c2 + 7) >> 3) - sy, 2);
        const int w = max(((c3 + 7) >> 3) - sx, 2);
        const int by = bin >> 1, bx = bin & 1;
        // adaptive bin i covers [i*size/2, ((i+1)*size+1)/2)
        const int rs = by ? (h >> 1) : 0;
        const int re = by ? h : ((h + 1) >> 1);
        const int cs = bx ? (w >> 1) : 0;
        const int ce = bx ? w : ((w + 1) >> 1);
        const int nc = ce - cs;              // 1..12 cols
        float4 m = make_float4(-1e30f, -1e30f, -1e30f, -1e30f);
        for (int r = rs + rslot; r < re; r += 2) {
            const float4* row = fm4 +
                ((size_t)(sy + r) * FW + sx + cs) * (CCH/4) + cb + cg;
            #pragma unroll 4
            for (int cc = 0; cc < nc; ++cc) {
                const float4 v = row[(size_t)cc * (CCH/4)];
                m.x = fmaxf(m.x, v.x); m.y = fmaxf(m.y, v.y);
                m.z = fmaxf(m.z, v.z); m.w = fmaxf(m.w, v.w);
            }
        }
        sm[rslot][nl][cg] = m;
    }
    __syncthreads();
    if (t < 256) {
        const int nl = t >> 5, cg = t & 31;
        const float4 a = sm[0][nl][cg], b = sm[1][nl][cg];
        float4 o;
        o.x = fmaxf(a.x, b.x); o.y = fmaxf(a.y, b.y);
        o.z = fmaxf(a.z, b.z); o.w = fmaxf(a.w, b.w);
        *((float4*)&fsub[nl][cg * 4]) = o;   // 16B-aligned LDS store
    }
    __syncthreads();

    // ===== Phase C: GEMM chunk — part[kc][r0+r][j] over 128 k =====
    {
        const int half = t >> 8;             // K-half 0..1 (wave-uniform)
        const int j    = t & 255;
        if (j < HID) {
            float acc[8];
            #pragma unroll
            for (int r = 0; r < 8; ++r) acc[r] = 0.0f;
            const int kk0 = half * 64;
            const float* wp = W1 + (size_t)(k0 + kk0) * HID + j;  // coalesced in j
            #pragma unroll 8
            for (int kk = 0; kk < 64; ++kk) {
                const float wv = wp[(size_t)kk * HID];
                #pragma unroll
                for (int r = 0; r < 8; ++r)
                    acc[r] += fsub[r][kk0 + kk] * wv;   // LDS broadcast
            }
            #pragma unroll
            for (int r = 0; r < 8; ++r) pc[half][r][j] = acc[r];
        }
    }
    __syncthreads();
    if (t < HID) {
        float* pp = part + ((size_t)kc * NP + r0) * HID + t;
        #pragma unroll
        for (int r = 0; r < 8; ++r)
            pp[(size_t)r * HID] = pc[0][r][t] + pc[1][r][t];
    }
}

// ---------------- Kernel 2: reduce + layer2 + heads + postprocess --------
// One block (512 threads) per proposal; layer2 and heads are split over
// 2 K-halves (kc = t>>8, wave-uniform) to halve the serial load chains.
__global__ __launch_bounds__(512) void head_kernel(
    const float* __restrict__ part,
    const float* __restrict__ b1, const float* __restrict__ W2,
    const float* __restrict__ b2, const float* __restrict__ W3,
    const float* __restrict__ b3, const float* __restrict__ W4,
    const float* __restrict__ b4, const int* __restrict__ coords,
    float* __restrict__ out)
{
    __shared__ float h1s[HID];
    __shared__ float h2s[HID];
    __shared__ float p2[2][HID];
    __shared__ float hdp[2][21];
    __shared__ float hd[21];     // 16 reg + 5 cls
    const int n = blockIdx.x;
    const int t = threadIdx.x;
    const int kc = t >> 8;       // 0..1, wave-uniform
    const int j  = t & 255;
    if (t < HID) {
        float a = b1[t];
        #pragma unroll
        for (int c = 0; c < NKC; ++c)
            a += part[((size_t)c * NP + n) * HID + t];
        h1s[t] = fmaxf(a, 0.0f);
    }
    __syncthreads();
    if (j < HID) {
        const int k0 = kc * 100;
        float acc = 0.0f;
        #pragma unroll 10
        for (int k = 0; k < 100; ++k)
            acc += h1s[k0 + k] * W2[(k0 + k) * HID + j];
        p2[kc][j] = acc;
    }
    __syncthreads();
    if (t < HID) h2s[t] = fmaxf(p2[0][t] + p2[1][t] + b2[t], 0.0f);
    __syncthreads();
    if (j < 21) {
        const int k0 = kc * 100;
        float acc = 0.0f;
        if (j < 16) {
            #pragma unroll 5
            for (int k = 0; k < 100; ++k)
                acc += h2s[k0 + k] * W3[(k0 + k) * 16 + j];
        } else {
            const int ci = j - 16;
            #pragma unroll 5
            for (int k = 0; k < 100; ++k)
                acc += h2s[k0 + k] * W4[(k0 + k) * 5 + ci];
        }
        hdp[kc][j] = acc;
    }
    __syncthreads();
    if (t < 21)
        hd[t] = hdp[0][t] + hdp[1][t] + (t < 16 ? b3[t] : b4[t - 16]);
    __syncthreads();
    if (t == 0) {
        const float cv0 = hd[16], cv1 = hd[17], cv2 = hd[18],
                    cv3 = hd[19], cv4 = hd[20];
        // jnp.argmax: first occurrence of max -> strict '>'
        int cls = 0; float best = cv0;
        if (cv1 > best) { best = cv1; cls = 1; }
        if (cv2 > best) { best = cv2; cls = 2; }
        if (cv3 > best) { best = cv3; cls = 3; }
        if (cv4 > best) { best = cv4; cls = 4; }
        const float e0 = expf(cv0 - best), e1 = expf(cv1 - best),
                    e2 = expf(cv2 - best), e3 = expf(cv3 - best),
                    e4 = expf(cv4 - best);
        const float s = e0 + e1 + e2 + e3 + e4;
        const float score = fmaxf(fmaxf(e1, e2), fmaxf(e3, e4)) / s;
        const int ri = max(cls - 1, 0);
        const float rg0 = hd[ri*4+0], rg1 = hd[ri*4+1],
                    rg2 = hd[ri*4+2], rg3 = hd[ri*4+3];
        const float y0 = (float)coords[n*4+0], x0 = (float)coords[n*4+1];
        const float y1 = (float)coords[n*4+2], x1 = (float)coords[n*4+3];
        const float ph = y1 - y0, pw = x1 - x0;
        const float py = y0 + 0.5f * ph, px = x0 + 0.5f * pw;
        const float oy = ph * rg0 + py;
        const float ox = pw * rg1 + px;
        const float oh = ph * fminf(fmaxf(expf(rg2), 0.001f), 20.0f);
        const float ow = pw * fminf(fmaxf(expf(rg3), 0.001f), 20.0f);
        out[n*4+0] = oy; out[n*4+1] = ox; out[n*4+2] = oh; out[n*4+3] = ow;
        out[NP*4 + n] = score;                       // scores block
        out[NP*5 + n] = (cls != 0) ? 1.0f : 0.0f;    // mask block (bool as fp32)
    }
}

extern "C" void kernel_launch(void* const* d_in, const int* in_sizes, int n_in,
                              void* d_out, int out_size, void* d_ws, size_t ws_size,
                              hipStream_t stream) {
    const float* fm     = (const float*)d_in[0];   // [1,76,128,512]
    const int*   coords = (const int*)  d_in[1];   // [256,4]
    const float* W1 = (const float*)d_in[2];       // [2048,200]
    const float* b1 = (const float*)d_in[3];
    const float* W2 = (const float*)d_in[4];       // [200,200]
    const float* b2 = (const float*)d_in[5];
    const float* W3 = (const float*)d_in[6];       // [200,16]
    const float* b3 = (const float*)d_in[7];
    const float* W4 = (const float*)d_in[8];       // [200,5]
    const float* b4 = (const float*)d_in[9];
    float* out = (float*)d_out;                    // 1024 boxes + 256 scores + 256 mask

    float* part    = (float*)d_ws;                 // [16, 256, 200]
    float* scratch = part + (size_t)NKC * NP * HID;

    poolgemm_kernel<<<dim3(32, NKC), 512, 0, stream>>>(
        (const float4*)fm, coords, W1, part, scratch);
    head_kernel<<<NP, 512, 0, stream>>>(part, b1, W2, b2, W3, b3, W4, b4,
                                        coords, out);
}